// Round 5
// baseline (610.394 us; speedup 1.0000x reference)
//
#include <hip/hip_runtime.h>
#include <hip/hip_bf16.h>
#include <cstdint>
#include <cstddef>

// Problem constants
#define NP     100352      // 32*56*56 total pixels
#define HW     3136        // 56*56
#define CDIM   384
#define C3     1152        // 3*384
#define NHEAD  12
#define HD     32          // head dim
#define NWIN   2048        // 32 * 8 * 8 windows

typedef __attribute__((ext_vector_type(8))) short bf16x8;
typedef __attribute__((ext_vector_type(4))) float f32x4;

static __device__ __forceinline__ float bf2f(unsigned short u) {
    union { float f; uint32_t i; } v; v.i = ((uint32_t)u) << 16; return v.f;
}
static __device__ __forceinline__ unsigned short f2bf(float f) {
    union { float f; uint32_t i; } v; v.f = f;
    uint32_t r = v.i + 0x7FFFu + ((v.i >> 16) & 1u);   // round-nearest-even
    return (unsigned short)(r >> 16);
}
// pack two f32 -> bf16 pair (round-half-up; lo half = a)
static __device__ __forceinline__ uint32_t pk2(float a, float b) {
    union { float f; uint32_t u; } x, y; x.f = a; y.f = b;
    return ((x.u + 0x8000u) >> 16) | ((y.u + 0x8000u) & 0xffff0000u);
}

// async global->LDS, 16B per lane; LDS dest = WAVE-UNIFORM base + lane*16
static __device__ __forceinline__ void gld_lds16(const void* g, void* l) {
    __builtin_amdgcn_global_load_lds(
        (const __attribute__((address_space(1))) void*)g,
        (__attribute__((address_space(3))) void*)l, 16, 0, 0);
}

// ---------------------------------------------------------------------------
// Kernel 1: fp32 -> bf16 weight conversion (vectorized x4)
// ---------------------------------------------------------------------------
__global__ __launch_bounds__(256) void cvt_f32_bf16(
    const float* __restrict__ src, unsigned short* __restrict__ dst, int n4) {
    int i = blockIdx.x * blockDim.x + threadIdx.x;
    if (i < n4) {
        float4 v = ((const float4*)src)[i];
        ushort4 r;
        r.x = f2bf(v.x); r.y = f2bf(v.y); r.z = f2bf(v.z); r.w = f2bf(v.w);
        ((ushort4*)dst)[i] = r;
    }
}

// ---------------------------------------------------------------------------
// Kernel 1b: precompute bias_t[h][query][key] fp32 (64x64 padded, / scale,
// -1e30 on pads so softmax masking is free). 12*64*64 = 49152 elems.
// ---------------------------------------------------------------------------
__global__ __launch_bounds__(256) void bias_pre(
    const float* __restrict__ btab, float* __restrict__ bias_t) {
    int idx = blockIdx.x * 256 + threadIdx.x;
    int h = idx >> 12, query = (idx >> 6) & 63, key = idx & 63;
    float v = -1e30f;
    if (query < 49 && key < 49) {
        int ri = query / 7, rj = query % 7, mi = key / 7, mj = key % 7;
        v = btab[((ri - mi + 6) * 13 + (rj - mj + 6)) * NHEAD + h] * 5.656854249492381f;
    }
    bias_t[idx] = v;
}

// ---------------------------------------------------------------------------
// Kernel 2: transpose x (B, C, HW) fp32 -> xt (B*HW, C) bf16
// grid (98, 12, 32), block (32, 8)
// ---------------------------------------------------------------------------
__global__ __launch_bounds__(256) void transpose_x(
    const float* __restrict__ x, unsigned short* __restrict__ xt) {
    __shared__ float tile[32][33];
    int b   = blockIdx.z;
    int hw0 = blockIdx.x * 32;
    int c0  = blockIdx.y * 32;
    int tx = threadIdx.x, ty = threadIdx.y;
    const float* xp = x + (size_t)b * CDIM * HW;
#pragma unroll
    for (int i = 0; i < 4; i++) {
        int c = ty + i * 8;
        tile[c][tx] = xp[(size_t)(c0 + c) * HW + hw0 + tx];   // coalesced along hw
    }
    __syncthreads();
    unsigned short* xtp = xt + (size_t)b * HW * CDIM;
#pragma unroll
    for (int i = 0; i < 4; i++) {
        int r = ty + i * 8;                                   // local hw
        xtp[(size_t)(hw0 + r) * CDIM + c0 + tx] = f2bf(tile[tx][r]);  // coalesced along c
    }
}

// ---------------------------------------------------------------------------
// m201-template MFMA GEMM core. K = 384 = 12 K-tiles of BK=32.
// 512 threads = 8 waves (WM x WN), per-wave 128x64 output (8x4 16x16 frags).
// Ring of 3 LDS K-tile buffers ((BM+BN)*32 bf16 each; 3x40 KB = 120 KiB).
// Template phase order: {ds_read (pre-barrier, data readiness established by
// PREVIOUS phase's vmcnt+barrier) | stage (ahead-2) | barrier | lgkmcnt(0) |
// setprio(1) 16 MFMA setprio(0) | barrier}. vmcnt counted ONCE per K-tile
// (phase B): ledger issued = 5t+15, tile t+1 ready <=> outstanding <= 5.
// BK=32 => a wave's frag read = 16 consecutive rows x 64 B = contiguous
// 1024 B: ZERO bank conflicts, no swizzle, staging stays linear (gload_lds).
// Stage call s covers 128 rows: thread t -> row t/4, 16B-seg t&3; 5 calls
// per K-tile (BM/128 A-calls + BN/128 B-calls).
// ---------------------------------------------------------------------------
template<int BM, int BN, int WM, int WN>
static __device__ __forceinline__ void gemm8(
    const unsigned short* __restrict__ A, const unsigned short* __restrict__ Bt,
    int m0, int n0, unsigned short* lds, f32x4 acc[8][4]) {

    constexpr int ACALLS = BM / 128;       // A stage-calls per K-tile
    constexpr int BUFE   = (BM + BN) * 32; // elems per ring buffer
    static_assert(BM / WM == 128 && BN / WN == 64, "per-wave tile 128x64");
    static_assert((BM + BN) / 128 == 5, "5 stage calls per K-tile");

    const int tid  = threadIdx.x;
    const int wv   = tid >> 6;
    const int lane = tid & 63;
    const int wc = wv % WN, wr = wv / WN;
    const int lrow = lane & 15, lq = lane >> 4;
    const int srow = tid >> 2;              // staging row within 128-row call
    const int sseg = (tid & 3) << 3;        // staging 16B-seg (elems)

#pragma unroll
    for (int i = 0; i < 8; i++)
#pragma unroll
        for (int j = 0; j < 4; j++) acc[i][j] = (f32x4){0.f, 0.f, 0.f, 0.f};

    // stage call s of K-tile kt into ring buffer bufi (linear row-major LDS).
    auto stage_call = [&](int s, int kt, int bufi) {
        if (s < ACALLS) {
            int grow = m0 + s * 128 + srow;
            gld_lds16(A + (size_t)grow * 384 + kt * 32 + sseg,
                      lds + bufi * BUFE + s * 4096 + wv * 512);
        } else {
            int sj = s - ACALLS;
            int grow = n0 + sj * 128 + srow;
            gld_lds16(Bt + (size_t)grow * 384 + kt * 32 + sseg,
                      lds + bufi * BUFE + BM * 32 + sj * 4096 + wv * 512);
        }
    };

    // prologue: stage K-tiles 0,1 (10 loads/wave); publish tile 0
#pragma unroll
    for (int s = 0; s < 5; s++) stage_call(s, 0, 0);
#pragma unroll
    for (int s = 0; s < 5; s++) stage_call(s, 1, 1);
    asm volatile("s_waitcnt vmcnt(5)" ::: "memory");
    __builtin_amdgcn_sched_barrier(0);
    __builtin_amdgcn_s_barrier();

#pragma unroll
    for (int t = 0; t < 12; t++) {
        const int bufi = t % 3, nbuf = (t + 2) % 3;
        const unsigned short* la = lds + bufi * BUFE;
        const unsigned short* lb = la + BM * 32;
        bf16x8 af[8], bfr[4];

        // ---------------- phase A (frag rows 0..63, 16 MFMA) ----------------
#pragma unroll
        for (int mi = 0; mi < 4; mi++)
            af[mi] = *(const bf16x8*)(la + (wr * 128 + mi * 16 + lrow) * 32 + lq * 8);
#pragma unroll
        for (int ni = 0; ni < 4; ni++)
            bfr[ni] = *(const bf16x8*)(lb + (wc * 64 + ni * 16 + lrow) * 32 + lq * 8);
        if (t < 10) { stage_call(0, t + 2, nbuf); stage_call(1, t + 2, nbuf);
                      stage_call(2, t + 2, nbuf); }
        __builtin_amdgcn_s_barrier();
        asm volatile("s_waitcnt lgkmcnt(0)" ::: "memory");
        __builtin_amdgcn_sched_barrier(0);
        __builtin_amdgcn_s_setprio(1);
#pragma unroll
        for (int mi = 0; mi < 4; mi++)
#pragma unroll
            for (int ni = 0; ni < 4; ni++)
                acc[mi][ni] = __builtin_amdgcn_mfma_f32_16x16x32_bf16(
                    af[mi], bfr[ni], acc[mi][ni], 0, 0, 0);
        __builtin_amdgcn_s_setprio(0);
        __builtin_amdgcn_s_barrier();

        // ---------------- phase B (frag rows 64..127, 16 MFMA) --------------
#pragma unroll
        for (int mi = 4; mi < 8; mi++)
            af[mi] = *(const bf16x8*)(la + (wr * 128 + mi * 16 + lrow) * 32 + lq * 8);
        if (t < 10) { stage_call(3, t + 2, nbuf); stage_call(4, t + 2, nbuf); }
        // counted wait publishes tile t+1 (ledger: outstanding<=5)
        if (t < 10)       { asm volatile("s_waitcnt vmcnt(5)" ::: "memory"); }
        else if (t == 10) { asm volatile("s_waitcnt vmcnt(0)" ::: "memory"); }
        __builtin_amdgcn_sched_barrier(0);
        __builtin_amdgcn_s_barrier();
        asm volatile("s_waitcnt lgkmcnt(0)" ::: "memory");
        __builtin_amdgcn_sched_barrier(0);
        __builtin_amdgcn_s_setprio(1);
#pragma unroll
        for (int mi = 4; mi < 8; mi++)
#pragma unroll
            for (int ni = 0; ni < 4; ni++)
                acc[mi][ni] = __builtin_amdgcn_mfma_f32_16x16x32_bf16(
                    af[mi], bfr[ni], acc[mi][ni], 0, 0, 0);
        __builtin_amdgcn_s_setprio(0);
        __builtin_amdgcn_s_barrier();   // WAR guard: buf t may be restaged at t+1
    }
}

// GEMM 1: qkv_t[p][o] = sum_c xt[p][c] * w_qkv[o][c]; output bf16, ldc = 1152
// BM=512 (p) x BN=128 (o), waves 4Mx2N. Grid 196*9 = 1764 = 8*220+4 ->
// bijective m204 XCD chunking; 9 n-tiles sharing one A-panel adjacent.
__global__ __launch_bounds__(512) void gemm_qkv9(
    const unsigned short* __restrict__ A, const unsigned short* __restrict__ Bt,
    unsigned short* __restrict__ C) {
    __shared__ __align__(16) unsigned short lds[3 * (512 + 128) * 32];  // 120 KiB
    int lin = blockIdx.x;
    int xcd = lin & 7, pos = lin >> 3;
    int nid = (xcd < 4 ? xcd * 221 : 884 + (xcd - 4) * 220) + pos;   // bijective
    int m0 = (nid / 9) * 512;
    int n0 = (nid % 9) * 128;
    f32x4 acc[8][4];
    gemm8<512, 128, 4, 2>(A, Bt, m0, n0, lds, acc);

    int lane = threadIdx.x & 63, wv = threadIdx.x >> 6;
    int wc = wv % 2, wr = wv / 2;
    int lrow = lane & 15, lq = lane >> 4;
#pragma unroll
    for (int mi = 0; mi < 8; mi++)
#pragma unroll
        for (int ni = 0; ni < 4; ni++)
#pragma unroll
            for (int i = 0; i < 4; i++) {
                int row = m0 + wr * 128 + mi * 16 + lq * 4 + i;  // p
                int col = n0 + wc * 64 + ni * 16 + lrow;         // o
                C[(size_t)row * C3 + col] = f2bf(acc[mi][ni][i]);
            }
}

// GEMM 2: out[b][o][hw] = sum_c w_proj[o][c] * out_t[p][c] + b_proj[o]
// BM=128 (o) x BN=512 (p), waves 1Mx8N. Grid 3*196 = 588 = 8*73+4 ->
// bijective m204 chunking; 3 m-blocks sharing one outt panel adjacent.
__global__ __launch_bounds__(512) void gemm_proj9(
    const unsigned short* __restrict__ A, const unsigned short* __restrict__ Bt,
    const float* __restrict__ bias, float* __restrict__ out) {
    __shared__ __align__(16) unsigned short lds[3 * (128 + 512) * 32];  // 120 KiB
    int lin = blockIdx.x;
    int xcd = lin & 7, pos = lin >> 3;
    int nid = (xcd < 4 ? xcd * 74 : 296 + (xcd - 4) * 73) + pos;     // bijective
    int m0 = (nid % 3) * 128;
    int n0 = (nid / 3) * 512;
    f32x4 acc[8][4];
    gemm8<128, 512, 1, 8>(A, Bt, m0, n0, lds, acc);

    int lane = threadIdx.x & 63, wv = threadIdx.x >> 6;
    int wc = wv;                       // WN=8, wr=0
    int lrow = lane & 15, lq = lane >> 4;
#pragma unroll
    for (int mi = 0; mi < 8; mi++)
#pragma unroll
        for (int ni = 0; ni < 4; ni++) {
            int pcol = n0 + wc * 64 + ni * 16 + lrow;            // global pixel p
            int b = pcol / HW, hw = pcol - b * HW;
#pragma unroll
            for (int i = 0; i < 4; i++) {
                int o = m0 + mi * 16 + lq * 4 + i;
                out[(size_t)b * CDIM * HW + (size_t)o * HW + hw] = acc[mi][ni][i] + bias[o];
            }
        }
}

// ---------------------------------------------------------------------------
// Kernel 4: MFMA window attention. grid (2048, 12), block 64 (1 wave).
// (unchanged this round)
// ---------------------------------------------------------------------------
__global__ __launch_bounds__(64, 3) void attn_mfma(
    const unsigned short* __restrict__ qkv, const float* __restrict__ bias_t,
    unsigned short* __restrict__ outt) {
    int w = blockIdx.x, h = blockIdx.y;
    int lane = threadIdx.x;
    int q = lane >> 4, c15 = lane & 15;
    int b = w >> 6, wy = (w >> 3) & 7, wx = w & 7;
    int pbase = b * HW + wy * 7 * 56 + wx * 7;

    __shared__ __align__(16) unsigned short sVT[32 * 72];  // V^T[d][key]
    __shared__ __align__(16) unsigned short sP[64 * 72];   // P[query][key]

    int p_t[4]; int valid[4];
#pragma unroll
    for (int t = 0; t < 4; t++) {
        int tok = c15 + 16 * t;
        valid[t] = tok < 49;
        int tc = valid[t] ? tok : 48;
        p_t[t] = pbase + (tc / 7) * 56 + (tc % 7);
    }

    {
        uint4* z = (uint4*)sVT;
#pragma unroll
        for (int i = 0; i < 5; i++) {
            int idx = lane + 64 * i;
            if (idx < 288) z[idx] = (uint4){0u, 0u, 0u, 0u};
        }
    }

    bf16x8 kf[4], qf[4];
#pragma unroll
    for (int t = 0; t < 4; t++) {
        const unsigned short* base = qkv + (size_t)p_t[t] * C3 + h * HD + q * 8;
        qf[t] = *(const bf16x8*)(base);
        kf[t] = *(const bf16x8*)(base + CDIM);
    }

#pragma unroll
    for (int it = 0; it < 4; it++) {
        int c = lane + 64 * it;
        if (c < 196) {
            int tok = c >> 2, s = c & 3;
            int p = pbase + (tok / 7) * 56 + (tok % 7);
            uint4 v = *(const uint4*)(qkv + (size_t)p * C3 + 2 * CDIM + h * HD + s * 8);
            const unsigned short* vp = (const unsigned short*)&v;
#pragma unroll
            for (int i = 0; i < 8; i++)
                sVT[(8 * s + i) * 72 + tok] = vp[i];
        }
    }

    f32x4 acc[4][4];
    const float* bp = bias_t + (size_t)h * 64 * 64;
#pragma unroll
    for (int nt = 0; nt < 4; nt++) {
        const float* bq = bp + (c15 + 16 * nt) * 64 + 4 * q;
#pragma unroll
        for (int mt = 0; mt < 4; mt++)
            acc[mt][nt] = *(const f32x4*)(bq + 16 * mt);
    }

#pragma unroll
    for (int mt = 0; mt < 4; mt++)
#pragma unroll
        for (int nt = 0; nt < 4; nt++)
            acc[mt][nt] = __builtin_amdgcn_mfma_f32_16x16x32_bf16(
                kf[mt], qf[nt], acc[mt][nt], 0, 0, 0);

    const float KSC = 0.25503472f;                // 2^-2.5 * log2(e)
#pragma unroll
    for (int nt = 0; nt < 4; nt++) {
        float mx = acc[0][nt][0];
#pragma unroll
        for (int mt = 0; mt < 4; mt++)
#pragma unroll
            for (int r = 0; r < 4; r++) mx = fmaxf(mx, acc[mt][nt][r]);
        mx = fmaxf(mx, __shfl_xor(mx, 16));
        mx = fmaxf(mx, __shfl_xor(mx, 32));
        float sum = 0.f;
#pragma unroll
        for (int mt = 0; mt < 4; mt++)
#pragma unroll
            for (int r = 0; r < 4; r++) {
                float e = exp2f((acc[mt][nt][r] - mx) * KSC);
                acc[mt][nt][r] = e;
                sum += e;
            }
        sum += __shfl_xor(sum, 16);
        sum += __shfl_xor(sum, 32);
        float inv = 1.0f / sum;
#pragma unroll
        for (int mt = 0; mt < 4; mt++) {
            uint32_t u01 = pk2(acc[mt][nt][0] * inv, acc[mt][nt][1] * inv);
            uint32_t u23 = pk2(acc[mt][nt][2] * inv, acc[mt][nt][3] * inv);
            *(uint2*)(sP + (c15 + 16 * nt) * 72 + 4 * q + 16 * mt) =
                make_uint2(u01, u23);
        }
    }

    bf16x8 pf[4][2], vf[2][2];
#pragma unroll
    for (int nt = 0; nt < 4; nt++)
#pragma unroll
        for (int ks = 0; ks < 2; ks++)
            pf[nt][ks] = *(const bf16x8*)(sP + (c15 + 16 * nt) * 72 + q * 8 + 32 * ks);
#pragma unroll
    for (int mt = 0; mt < 2; mt++)
#pragma unroll
        for (int ks = 0; ks < 2; ks++)
            vf[mt][ks] = *(const bf16x8*)(sVT + (c15 + 16 * mt) * 72 + q * 8 + 32 * ks);

    f32x4 oacc[2][4];
#pragma unroll
    for (int mt = 0; mt < 2; mt++)
#pragma unroll
        for (int nt = 0; nt < 4; nt++)
            oacc[mt][nt] = (f32x4){0.f, 0.f, 0.f, 0.f};
#pragma unroll
    for (int ks = 0; ks < 2; ks++)
#pragma unroll
        for (int mt = 0; mt < 2; mt++)
#pragma unroll
            for (int nt = 0; nt < 4; nt++)
                oacc[mt][nt] = __builtin_amdgcn_mfma_f32_16x16x32_bf16(
                    vf[mt][ks], pf[nt][ks], oacc[mt][nt], 0, 0, 0);

#pragma unroll
    for (int nt = 0; nt < 4; nt++) {
        if (valid[nt]) {
            unsigned short* dst = outt + (size_t)p_t[nt] * CDIM + h * HD + 4 * q;
#pragma unroll
            for (int mt = 0; mt < 2; mt++) {
                uint32_t u01 = pk2(oacc[mt][nt][0], oacc[mt][nt][1]);
                uint32_t u23 = pk2(oacc[mt][nt][2], oacc[mt][nt][3]);
                *(uint2*)(dst + 16 * mt) = make_uint2(u01, u23);
            }
        }
    }
}

// ---------------------------------------------------------------------------
// Launch
// ---------------------------------------------------------------------------
extern "C" void kernel_launch(void* const* d_in, const int* in_sizes, int n_in,
                              void* d_out, int out_size, void* d_ws, size_t ws_size,
                              hipStream_t stream) {
    const float* x      = (const float*)d_in[0];
    const float* w_qkv  = (const float*)d_in[1];
    const float* btab   = (const float*)d_in[2];
    const float* w_proj = (const float*)d_in[3];
    const float* b_proj = (const float*)d_in[4];
    float* out = (float*)d_out;

    // workspace layout (bytes)
    char* ws = (char*)d_ws;
    const size_t off_xt   = 0;                         // 77,070,336 (reused as out_t)
    const size_t off_qkv  = 77070336;                  // 231,211,008
    const size_t off_wq   = off_qkv + 231211008;       // 884,736
    const size_t off_wp   = off_wq + 884736;           // 294,912
    const size_t off_bt   = off_wp + 294912;           // 196,608
    unsigned short* xt   = (unsigned short*)(ws + off_xt);
    unsigned short* qkvt = (unsigned short*)(ws + off_qkv);
    unsigned short* wqb  = (unsigned short*)(ws + off_wq);
    unsigned short* wpb  = (unsigned short*)(ws + off_wp);
    float*          bt   = (float*)(ws + off_bt);
    unsigned short* outt = xt;   // alias: xt dead after gemm_qkv

    cvt_f32_bf16<<<(C3 * CDIM / 4 + 255) / 256, 256, 0, stream>>>(w_qkv, wqb, C3 * CDIM / 4);
    cvt_f32_bf16<<<(CDIM * CDIM / 4 + 255) / 256, 256, 0, stream>>>(w_proj, wpb, CDIM * CDIM / 4);
    bias_pre<<<192, 256, 0, stream>>>(btab, bt);
    transpose_x<<<dim3(98, 12, 32), dim3(32, 8), 0, stream>>>(x, xt);
    gemm_qkv9<<<1764, 512, 0, stream>>>(xt, wqb, qkvt);
    attn_mfma<<<dim3(NWIN, NHEAD), 64, 0, stream>>>(qkvt, bt, outt);
    gemm_proj9<<<588, 512, 0, stream>>>(wpb, outt, b_proj, out);
}

// Round 6
// 590.303 us; speedup vs baseline: 1.0340x; 1.0340x over previous
//
#include <hip/hip_runtime.h>
#include <hip/hip_bf16.h>
#include <cstdint>
#include <cstddef>

// Problem constants
#define NP     100352      // 32*56*56 total pixels
#define HW     3136        // 56*56
#define CDIM   384
#define C3     1152        // 3*384
#define NHEAD  12
#define HD     32          // head dim
#define NWIN   2048        // 32 * 8 * 8 windows

typedef __attribute__((ext_vector_type(8))) short bf16x8;
typedef __attribute__((ext_vector_type(4))) float f32x4;

static __device__ __forceinline__ float bf2f(unsigned short u) {
    union { float f; uint32_t i; } v; v.i = ((uint32_t)u) << 16; return v.f;
}
static __device__ __forceinline__ unsigned short f2bf(float f) {
    union { float f; uint32_t i; } v; v.f = f;
    uint32_t r = v.i + 0x7FFFu + ((v.i >> 16) & 1u);   // round-nearest-even
    return (unsigned short)(r >> 16);
}
// pack two f32 -> bf16 pair (round-half-up; lo half = a)
static __device__ __forceinline__ uint32_t pk2(float a, float b) {
    union { float f; uint32_t u; } x, y; x.f = a; y.f = b;
    return ((x.u + 0x8000u) >> 16) | ((y.u + 0x8000u) & 0xffff0000u);
}

// async global->LDS, 16B per lane; LDS dest = WAVE-UNIFORM base + lane*16
static __device__ __forceinline__ void gld_lds16(const void* g, void* l) {
    __builtin_amdgcn_global_load_lds(
        (const __attribute__((address_space(1))) void*)g,
        (__attribute__((address_space(3))) void*)l, 16, 0, 0);
}

// ---------------------------------------------------------------------------
// Kernel 1: fp32 -> bf16 weight conversion (vectorized x4)
// ---------------------------------------------------------------------------
__global__ __launch_bounds__(256) void cvt_f32_bf16(
    const float* __restrict__ src, unsigned short* __restrict__ dst, int n4) {
    int i = blockIdx.x * blockDim.x + threadIdx.x;
    if (i < n4) {
        float4 v = ((const float4*)src)[i];
        ushort4 r;
        r.x = f2bf(v.x); r.y = f2bf(v.y); r.z = f2bf(v.z); r.w = f2bf(v.w);
        ((ushort4*)dst)[i] = r;
    }
}

// ---------------------------------------------------------------------------
// Kernel 1b: precompute bias_t[h][query][key] fp32 (64x64 padded, / scale,
// -1e30 on pads so softmax masking is free). 12*64*64 = 49152 elems.
// ---------------------------------------------------------------------------
__global__ __launch_bounds__(256) void bias_pre(
    const float* __restrict__ btab, float* __restrict__ bias_t) {
    int idx = blockIdx.x * 256 + threadIdx.x;
    int h = idx >> 12, query = (idx >> 6) & 63, key = idx & 63;
    float v = -1e30f;
    if (query < 49 && key < 49) {
        int ri = query / 7, rj = query % 7, mi = key / 7, mj = key % 7;
        v = btab[((ri - mi + 6) * 13 + (rj - mj + 6)) * NHEAD + h] * 5.656854249492381f;
    }
    bias_t[idx] = v;
}

// ---------------------------------------------------------------------------
// Kernel 2: transpose x (B, C, HW) fp32 -> xt (B*HW, C) bf16
// grid (98, 12, 32), block (32, 8)
// ---------------------------------------------------------------------------
__global__ __launch_bounds__(256) void transpose_x(
    const float* __restrict__ x, unsigned short* __restrict__ xt) {
    __shared__ float tile[32][33];
    int b   = blockIdx.z;
    int hw0 = blockIdx.x * 32;
    int c0  = blockIdx.y * 32;
    int tx = threadIdx.x, ty = threadIdx.y;
    const float* xp = x + (size_t)b * CDIM * HW;
#pragma unroll
    for (int i = 0; i < 4; i++) {
        int c = ty + i * 8;
        tile[c][tx] = xp[(size_t)(c0 + c) * HW + hw0 + tx];   // coalesced along hw
    }
    __syncthreads();
    unsigned short* xtp = xt + (size_t)b * HW * CDIM;
#pragma unroll
    for (int i = 0; i < 4; i++) {
        int r = ty + i * 8;                                   // local hw
        xtp[(size_t)(hw0 + r) * CDIM + c0 + tx] = f2bf(tile[tx][r]);  // coalesced along c
    }
}

// ---------------------------------------------------------------------------
// 8-phase MFMA GEMM core (R4 structure — best measured loop: conflicts 0).
// K = 384 = 6 K-tiles of BK=64. 512 threads = 8 waves (WM x WN), per-wave
// 64x64 output. Ring of 3 LDS K-tile buffers. Staging 2 K-tiles ahead ->
// counted s_waitcnt vmcnt(9). Raw s_barrier. Slot-XOR swizzle on the READ
// side; inverse XOR pre-applied to per-lane GLOBAL source address.
// ---------------------------------------------------------------------------
template<int BM, int BN, int WM, int WN>
static __device__ __forceinline__ void gemm8(
    const unsigned short* __restrict__ A, const unsigned short* __restrict__ Bt,
    int m0, int n0, unsigned short* lds, f32x4 acc[4][4]) {

    constexpr int NA   = BM / 64;          // A stage-calls per K-tile (per thread)
    constexpr int BUFE = (BM + BN) * 64;   // elems per ring buffer

    const int tid  = threadIdx.x;
    const int wv   = tid >> 6;
    const int lane = tid & 63;
    const int wc = wv & (WN - 1), wr = wv / WN;
    const int lrow = lane & 15, lq = lane >> 4;
    const int lr8  = lane >> 3;                 // row within 8-row chunk
    const int gsl  = ((lane & 7) ^ lr8) << 3;   // inverse-swizzled slot, elems

#pragma unroll
    for (int i = 0; i < 4; i++)
#pragma unroll
        for (int j = 0; j < 4; j++) acc[i][j] = (f32x4){0.f, 0.f, 0.f, 0.f};

    auto stage = [&](int s, int kt, int bufi) {
        if (s < NA) {
            int grow = m0 + s * 64 + wv * 8 + lr8;
            gld_lds16(A + (size_t)grow * 384 + kt * 64 + gsl,
                      lds + bufi * BUFE + (s * 8 + wv) * 512);
        } else {
            int sj = s - NA;
            int grow = n0 + sj * 64 + wv * 8 + lr8;
            gld_lds16(Bt + (size_t)grow * 384 + kt * 64 + gsl,
                      lds + bufi * BUFE + BM * 64 + (sj * 8 + wv) * 512);
        }
    };

    // prologue: stage K-tiles 0 and 1 (12 loads outstanding per thread)
#pragma unroll
    for (int s = 0; s < 6; s++) stage(s, 0, 0);
#pragma unroll
    for (int s = 0; s < 6; s++) stage(s, 1, 1);

#pragma unroll
    for (int t = 0; t < 6; t++) {
        const int bufi = t % 3, nbuf = (t + 2) % 3;
        const unsigned short* la = lds + bufi * BUFE;
        const unsigned short* lb = la + BM * 64;
        bf16x8 af[4][2], bfr[2][2];

        // ------------- phase A (C cols 0..31 of wave tile) -------------
        if (t < 4) { stage(0, t + 2, nbuf); stage(1, t + 2, nbuf); stage(2, t + 2, nbuf); }
        if (t < 4)       asm volatile("s_waitcnt vmcnt(9)" ::: "memory");
        else if (t == 4) asm volatile("s_waitcnt vmcnt(6)" ::: "memory");
        else             asm volatile("s_waitcnt vmcnt(0)" ::: "memory");
        __builtin_amdgcn_sched_barrier(0);
        __builtin_amdgcn_s_barrier();   // collective: tile t ready everywhere

#pragma unroll
        for (int mi = 0; mi < 4; mi++)
#pragma unroll
            for (int ks = 0; ks < 2; ks++)
                af[mi][ks] = *(const bf16x8*)(la + (wr * 64 + mi * 16 + lrow) * 64 +
                                              (((ks * 4 + lq) ^ (lrow & 7)) << 3));
#pragma unroll
        for (int ni = 0; ni < 2; ni++)
#pragma unroll
            for (int ks = 0; ks < 2; ks++)
                bfr[ni][ks] = *(const bf16x8*)(lb + (wc * 64 + ni * 16 + lrow) * 64 +
                                               (((ks * 4 + lq) ^ (lrow & 7)) << 3));
        __builtin_amdgcn_s_setprio(1);
#pragma unroll
        for (int mi = 0; mi < 4; mi++)
#pragma unroll
            for (int ni = 0; ni < 2; ni++)
#pragma unroll
                for (int ks = 0; ks < 2; ks++)
                    acc[mi][ni] = __builtin_amdgcn_mfma_f32_16x16x32_bf16(
                        af[mi][ks], bfr[ni][ks], acc[mi][ni], 0, 0, 0);
        __builtin_amdgcn_s_setprio(0);
        __builtin_amdgcn_s_barrier();

        // ------------- phase B (C cols 32..63 of wave tile) -------------
        if (t < 4) { stage(3, t + 2, nbuf); stage(4, t + 2, nbuf); stage(5, t + 2, nbuf); }
        __builtin_amdgcn_s_barrier();
#pragma unroll
        for (int ni = 0; ni < 2; ni++)
#pragma unroll
            for (int ks = 0; ks < 2; ks++)
                bfr[ni][ks] = *(const bf16x8*)(lb + (wc * 64 + (ni + 2) * 16 + lrow) * 64 +
                                               (((ks * 4 + lq) ^ (lrow & 7)) << 3));
        __builtin_amdgcn_s_setprio(1);
#pragma unroll
        for (int mi = 0; mi < 4; mi++)
#pragma unroll
            for (int ni = 0; ni < 2; ni++)
#pragma unroll
                for (int ks = 0; ks < 2; ks++)
                    acc[mi][ni + 2] = __builtin_amdgcn_mfma_f32_16x16x32_bf16(
                        af[mi][ks], bfr[ni][ks], acc[mi][ni + 2], 0, 0, 0);
        __builtin_amdgcn_s_setprio(0);
        __builtin_amdgcn_s_barrier();
    }
}

// GEMM 1: qkv_t[p][o] = sum_c xt[p][c] * w_qkv[o][c]; output bf16, ldc = 1152
// BM=256 (p), BN=128 (o): grid 3528 = 8*441 (bijective XCD chunking).
// NEW: LDS-staged coalesced epilogue — acc -> LDS C-tile (64 KB, ring reused)
// -> cooperative uint4 stores, 256 B contiguous per row (was 2-B scalar
// stores in 32-B segments; write drain measured 1.45 TB/s => suspected floor).
__global__ __launch_bounds__(512) void gemm_qkv8(
    const unsigned short* __restrict__ A, const unsigned short* __restrict__ Bt,
    unsigned short* __restrict__ C) {
    __shared__ __align__(16) unsigned short lds[3 * (256 + 128) * 64];  // 144 KiB
    int lin = blockIdx.x;
    int xcd = lin & 7, pos = lin >> 3;
    int nid = xcd * 441 + pos;              // bijective: 3528 = 8*441
    int m0 = (nid / 9) * 256;
    int n0 = (nid % 9) * 128;
    f32x4 acc[4][4];
    gemm8<256, 128, 4, 2>(A, Bt, m0, n0, lds, acc);

    int lane = threadIdx.x & 63, wv = threadIdx.x >> 6;
    int wc = wv & 1, wr = wv >> 1;
    int lrow = lane & 15, lq = lane >> 4;

    // stage C-tile (256 x 128 bf16 = 64 KB) into LDS (free after final barrier)
    unsigned short* sC = lds;
#pragma unroll
    for (int mi = 0; mi < 4; mi++)
#pragma unroll
        for (int ni = 0; ni < 4; ni++)
#pragma unroll
            for (int i = 0; i < 4; i++) {
                int row = wr * 64 + mi * 16 + lq * 4 + i;   // local p
                int col = wc * 64 + ni * 16 + lrow;         // local o
                sC[row * 128 + col] = f2bf(acc[mi][ni][i]);
            }
    __syncthreads();
    // cooperative coalesced store: 256 rows x 256 B contiguous
    int r0  = threadIdx.x >> 4;    // 0..31
    int seg = threadIdx.x & 15;    // 16B segment within row
#pragma unroll
    for (int pass = 0; pass < 8; pass++) {
        int row = pass * 32 + r0;
        uint4 v = *(const uint4*)(sC + row * 128 + seg * 8);
        *(uint4*)(C + (size_t)(m0 + row) * C3 + n0 + seg * 8) = v;
    }
}

// GEMM 2: out[b][o][hw] = sum_c w_proj[o][c] * out_t[p][c] + b_proj[o]
// BM=128 (o), BN=256 (p): grid 1176 = 8*147.
// NEW: LDS-staged coalesced epilogue — f32 C-tile (128 KB) -> float4 stores,
// 1 KB contiguous per o-row along hw (float4 never straddles batch: 3136%4==0).
__global__ __launch_bounds__(512) void gemm_proj8(
    const unsigned short* __restrict__ A, const unsigned short* __restrict__ Bt,
    const float* __restrict__ bias, float* __restrict__ out) {
    __shared__ __align__(16) unsigned short lds[3 * (128 + 256) * 64];  // 144 KiB
    int lin = blockIdx.x;
    int xcd = lin & 7, pos = lin >> 3;
    int nid = xcd * 147 + pos;              // bijective: 1176 = 8*147
    int m0 = (nid % 3) * 128;
    int n0 = (nid / 3) * 256;
    f32x4 acc[4][4];
    gemm8<128, 256, 2, 4>(A, Bt, m0, n0, lds, acc);

    int lane = threadIdx.x & 63, wv = threadIdx.x >> 6;
    int wc = wv & 3, wr = wv >> 2;
    int lrow = lane & 15, lq = lane >> 4;

    // stage C-tile (128 o x 256 p f32 = 128 KB) into LDS, bias folded
    float* sCf = (float*)lds;
#pragma unroll
    for (int mi = 0; mi < 4; mi++)
#pragma unroll
        for (int ni = 0; ni < 4; ni++)
#pragma unroll
            for (int i = 0; i < 4; i++) {
                int row = wr * 64 + mi * 16 + lq * 4 + i;   // local o
                int col = wc * 64 + ni * 16 + lrow;         // local p
                sCf[row * 256 + col] = acc[mi][ni][i] + bias[m0 + row];
            }
    __syncthreads();
    // cooperative coalesced store: per o-row, 256 p x 4 B = 1 KB along hw
    int r0   = threadIdx.x >> 6;   // 0..7
    int slot = threadIdx.x & 63;   // float4 slot
#pragma unroll
    for (int pass = 0; pass < 16; pass++) {
        int row = pass * 8 + r0;               // local o
        int p4  = n0 + slot * 4;               // global pixel (4-aligned)
        int b   = p4 / HW, hw = p4 - b * HW;   // float4 never straddles b
        float4 v = *(const float4*)(sCf + row * 256 + slot * 4);
        *(float4*)(out + (size_t)b * CDIM * HW + (size_t)(m0 + row) * HW + hw) = v;
    }
}

// ---------------------------------------------------------------------------
// Kernel 4: MFMA window attention. grid (2048, 12), block 64 (1 wave).
// (unchanged this round)
// ---------------------------------------------------------------------------
__global__ __launch_bounds__(64, 3) void attn_mfma(
    const unsigned short* __restrict__ qkv, const float* __restrict__ bias_t,
    unsigned short* __restrict__ outt) {
    int w = blockIdx.x, h = blockIdx.y;
    int lane = threadIdx.x;
    int q = lane >> 4, c15 = lane & 15;
    int b = w >> 6, wy = (w >> 3) & 7, wx = w & 7;
    int pbase = b * HW + wy * 7 * 56 + wx * 7;

    __shared__ __align__(16) unsigned short sVT[32 * 72];  // V^T[d][key]
    __shared__ __align__(16) unsigned short sP[64 * 72];   // P[query][key]

    int p_t[4]; int valid[4];
#pragma unroll
    for (int t = 0; t < 4; t++) {
        int tok = c15 + 16 * t;
        valid[t] = tok < 49;
        int tc = valid[t] ? tok : 48;
        p_t[t] = pbase + (tc / 7) * 56 + (tc % 7);
    }

    {
        uint4* z = (uint4*)sVT;
#pragma unroll
        for (int i = 0; i < 5; i++) {
            int idx = lane + 64 * i;
            if (idx < 288) z[idx] = (uint4){0u, 0u, 0u, 0u};
        }
    }

    bf16x8 kf[4], qf[4];
#pragma unroll
    for (int t = 0; t < 4; t++) {
        const unsigned short* base = qkv + (size_t)p_t[t] * C3 + h * HD + q * 8;
        qf[t] = *(const bf16x8*)(base);
        kf[t] = *(const bf16x8*)(base + CDIM);
    }

#pragma unroll
    for (int it = 0; it < 4; it++) {
        int c = lane + 64 * it;
        if (c < 196) {
            int tok = c >> 2, s = c & 3;
            int p = pbase + (tok / 7) * 56 + (tok % 7);
            uint4 v = *(const uint4*)(qkv + (size_t)p * C3 + 2 * CDIM + h * HD + s * 8);
            const unsigned short* vp = (const unsigned short*)&v;
#pragma unroll
            for (int i = 0; i < 8; i++)
                sVT[(8 * s + i) * 72 + tok] = vp[i];
        }
    }

    f32x4 acc[4][4];
    const float* bp = bias_t + (size_t)h * 64 * 64;
#pragma unroll
    for (int nt = 0; nt < 4; nt++) {
        const float* bq = bp + (c15 + 16 * nt) * 64 + 4 * q;
#pragma unroll
        for (int mt = 0; mt < 4; mt++)
            acc[mt][nt] = *(const f32x4*)(bq + 16 * mt);
    }

#pragma unroll
    for (int mt = 0; mt < 4; mt++)
#pragma unroll
        for (int nt = 0; nt < 4; nt++)
            acc[mt][nt] = __builtin_amdgcn_mfma_f32_16x16x32_bf16(
                kf[mt], qf[nt], acc[mt][nt], 0, 0, 0);

    const float KSC = 0.25503472f;                // 2^-2.5 * log2(e)
#pragma unroll
    for (int nt = 0; nt < 4; nt++) {
        float mx = acc[0][nt][0];
#pragma unroll
        for (int mt = 0; mt < 4; mt++)
#pragma unroll
            for (int r = 0; r < 4; r++) mx = fmaxf(mx, acc[mt][nt][r]);
        mx = fmaxf(mx, __shfl_xor(mx, 16));
        mx = fmaxf(mx, __shfl_xor(mx, 32));
        float sum = 0.f;
#pragma unroll
        for (int mt = 0; mt < 4; mt++)
#pragma unroll
            for (int r = 0; r < 4; r++) {
                float e = exp2f((acc[mt][nt][r] - mx) * KSC);
                acc[mt][nt][r] = e;
                sum += e;
            }
        sum += __shfl_xor(sum, 16);
        sum += __shfl_xor(sum, 32);
        float inv = 1.0f / sum;
#pragma unroll
        for (int mt = 0; mt < 4; mt++) {
            uint32_t u01 = pk2(acc[mt][nt][0] * inv, acc[mt][nt][1] * inv);
            uint32_t u23 = pk2(acc[mt][nt][2] * inv, acc[mt][nt][3] * inv);
            *(uint2*)(sP + (c15 + 16 * nt) * 72 + 4 * q + 16 * mt) =
                make_uint2(u01, u23);
        }
    }

    bf16x8 pf[4][2], vf[2][2];
#pragma unroll
    for (int nt = 0; nt < 4; nt++)
#pragma unroll
        for (int ks = 0; ks < 2; ks++)
            pf[nt][ks] = *(const bf16x8*)(sP + (c15 + 16 * nt) * 72 + q * 8 + 32 * ks);
#pragma unroll
    for (int mt = 0; mt < 2; mt++)
#pragma unroll
        for (int ks = 0; ks < 2; ks++)
            vf[mt][ks] = *(const bf16x8*)(sVT + (c15 + 16 * mt) * 72 + q * 8 + 32 * ks);

    f32x4 oacc[2][4];
#pragma unroll
    for (int mt = 0; mt < 2; mt++)
#pragma unroll
        for (int nt = 0; nt < 4; nt++)
            oacc[mt][nt] = (f32x4){0.f, 0.f, 0.f, 0.f};
#pragma unroll
    for (int ks = 0; ks < 2; ks++)
#pragma unroll
        for (int mt = 0; mt < 2; mt++)
#pragma unroll
            for (int nt = 0; nt < 4; nt++)
                oacc[mt][nt] = __builtin_amdgcn_mfma_f32_16x16x32_bf16(
                    vf[mt][ks], pf[nt][ks], oacc[mt][nt], 0, 0, 0);

#pragma unroll
    for (int nt = 0; nt < 4; nt++) {
        if (valid[nt]) {
            unsigned short* dst = outt + (size_t)p_t[nt] * CDIM + h * HD + 4 * q;
#pragma unroll
            for (int mt = 0; mt < 2; mt++) {
                uint32_t u01 = pk2(oacc[mt][nt][0], oacc[mt][nt][1]);
                uint32_t u23 = pk2(oacc[mt][nt][2], oacc[mt][nt][3]);
                *(uint2*)(dst + 16 * mt) = make_uint2(u01, u23);
            }
        }
    }
}

// ---------------------------------------------------------------------------
// Launch
// ---------------------------------------------------------------------------
extern "C" void kernel_launch(void* const* d_in, const int* in_sizes, int n_in,
                              void* d_out, int out_size, void* d_ws, size_t ws_size,
                              hipStream_t stream) {
    const float* x      = (const float*)d_in[0];
    const float* w_qkv  = (const float*)d_in[1];
    const float* btab   = (const float*)d_in[2];
    const float* w_proj = (const float*)d_in[3];
    const float* b_proj = (const float*)d_in[4];
    float* out = (float*)d_out;

    // workspace layout (bytes)
    char* ws = (char*)d_ws;
    const size_t off_xt   = 0;                         // 77,070,336 (reused as out_t)
    const size_t off_qkv  = 77070336;                  // 231,211,008
    const size_t off_wq   = off_qkv + 231211008;       // 884,736
    const size_t off_wp   = off_wq + 884736;           // 294,912
    const size_t off_bt   = off_wp + 294912;           // 196,608
    unsigned short* xt   = (unsigned short*)(ws + off_xt);
    unsigned short* qkvt = (unsigned short*)(ws + off_qkv);
    unsigned short* wqb  = (unsigned short*)(ws + off_wq);
    unsigned short* wpb  = (unsigned short*)(ws + off_wp);
    float*          bt   = (float*)(ws + off_bt);
    unsigned short* outt = xt;   // alias: xt dead after gemm_qkv

    cvt_f32_bf16<<<(C3 * CDIM / 4 + 255) / 256, 256, 0, stream>>>(w_qkv, wqb, C3 * CDIM / 4);
    cvt_f32_bf16<<<(CDIM * CDIM / 4 + 255) / 256, 256, 0, stream>>>(w_proj, wpb, CDIM * CDIM / 4);
    bias_pre<<<192, 256, 0, stream>>>(btab, bt);
    transpose_x<<<dim3(98, 12, 32), dim3(32, 8), 0, stream>>>(x, xt);
    gemm_qkv8<<<3528, 512, 0, stream>>>(xt, wqb, qkvt);
    attn_mfma<<<dim3(NWIN, NHEAD), 64, 0, stream>>>(qkvt, bt, outt);
    gemm_proj8<<<1176, 512, 0, stream>>>(wpb, outt, b_proj, out);
}

// Round 7
// 581.625 us; speedup vs baseline: 1.0495x; 1.0149x over previous
//
#include <hip/hip_runtime.h>
#include <hip/hip_bf16.h>
#include <cstdint>
#include <cstddef>

// Problem constants
#define NP     100352      // 32*56*56 total pixels
#define HW     3136        // 56*56
#define CDIM   384
#define C3     1152        // 3*384
#define NHEAD  12
#define HD     32          // head dim
#define NWIN   2048        // 32 * 8 * 8 windows

typedef __attribute__((ext_vector_type(8))) short bf16x8;
typedef __attribute__((ext_vector_type(4))) float f32x4;

static __device__ __forceinline__ float bf2f(unsigned short u) {
    union { float f; uint32_t i; } v; v.i = ((uint32_t)u) << 16; return v.f;
}
static __device__ __forceinline__ unsigned short f2bf(float f) {
    union { float f; uint32_t i; } v; v.f = f;
    uint32_t r = v.i + 0x7FFFu + ((v.i >> 16) & 1u);   // round-nearest-even
    return (unsigned short)(r >> 16);
}
// pack two f32 -> bf16 pair (round-half-up; lo half = a)
static __device__ __forceinline__ uint32_t pk2(float a, float b) {
    union { float f; uint32_t u; } x, y; x.f = a; y.f = b;
    return ((x.u + 0x8000u) >> 16) | ((y.u + 0x8000u) & 0xffff0000u);
}

// async global->LDS, 16B per lane; LDS dest = WAVE-UNIFORM base + lane*16
static __device__ __forceinline__ void gld_lds16(const void* g, void* l) {
    __builtin_amdgcn_global_load_lds(
        (const __attribute__((address_space(1))) void*)g,
        (__attribute__((address_space(3))) void*)l, 16, 0, 0);
}

// ---------------------------------------------------------------------------
// Kernel 1 (fused prep): weight cvts + bias table + x-transpose in ONE launch.
// blocks [0,432): w_qkv f32->bf16 (110592 float4)
// blocks [432,576): w_proj f32->bf16 (36864 float4)
// blocks [576,768): bias_t[h][query][key] fp32 64x64 padded (-1e30 pads)
// blocks [768,10176): transpose x (B,C,HW) f32 -> xt (B*HW, C) bf16,
//   32hw x 128c tiles, LDS-staged, uint4 (256-B/row) coalesced xt writes
//   (old version used 2-B scalar stores in 64-B segments => ~1.5 TB/s drain).
// ---------------------------------------------------------------------------
__global__ __launch_bounds__(256) void prep_transpose(
    const float* __restrict__ x, const float* __restrict__ w_qkv,
    const float* __restrict__ w_proj, const float* __restrict__ btab,
    unsigned short* __restrict__ wqb, unsigned short* __restrict__ wpb,
    float* __restrict__ bias_t, unsigned short* __restrict__ xt) {
    int bid = blockIdx.x;
    int tid = threadIdx.x;
    if (bid < 432) {                         // w_qkv cvt
        int i = bid * 256 + tid;             // 432*256 = 110592 exactly
        float4 v = ((const float4*)w_qkv)[i];
        ushort4 r;
        r.x = f2bf(v.x); r.y = f2bf(v.y); r.z = f2bf(v.z); r.w = f2bf(v.w);
        ((ushort4*)wqb)[i] = r;
    } else if (bid < 576) {                  // w_proj cvt
        int i = (bid - 432) * 256 + tid;     // 144*256 = 36864 exactly
        float4 v = ((const float4*)w_proj)[i];
        ushort4 r;
        r.x = f2bf(v.x); r.y = f2bf(v.y); r.z = f2bf(v.z); r.w = f2bf(v.w);
        ((ushort4*)wpb)[i] = r;
    } else if (bid < 768) {                  // bias precompute
        int idx = (bid - 576) * 256 + tid;   // 192*256 = 49152
        int h = idx >> 12, query = (idx >> 6) & 63, key = idx & 63;
        float v = -1e30f;
        if (query < 49 && key < 49) {
            int ri = query / 7, rj = query % 7, mi = key / 7, mj = key % 7;
            v = btab[((ri - mi + 6) * 13 + (rj - mj + 6)) * NHEAD + h] * 5.656854249492381f;
        }
        bias_t[idx] = v;
    } else {                                 // transpose tile
        __shared__ unsigned short tile[32][136];   // 272-B rows: 16-B aligned
        int t  = bid - 768;                  // 9408 tiles = 32 b * 3 c * 98 hw
        int b  = t / 294;
        int r  = t - b * 294;
        int c0  = (r / 98) * 128;
        int hw0 = (r % 98) * 32;
        int tx = tid & 31, ty = tid >> 5;    // ty 0..7
        const float* xp = x + ((size_t)b * CDIM + c0) * HW + hw0;
#pragma unroll
        for (int i = 0; i < 16; i++) {
            int c = i * 8 + ty;              // 0..127
            tile[tx][c] = f2bf(xp[(size_t)c * HW + tx]);   // coalesced read along hw
        }
        __syncthreads();
        int row2 = tid >> 4, seg = tid & 15; // 16 rows/pass, uint4 seg
        unsigned short* xtp = xt + ((size_t)(b * HW + hw0)) * CDIM + c0;
#pragma unroll
        for (int pass = 0; pass < 2; pass++) {
            int row = pass * 16 + row2;
            uint4 v = *(const uint4*)(&tile[row][seg * 8]);
            *(uint4*)(xtp + (size_t)row * CDIM + seg * 8) = v;   // 256-B/row burst
        }
    }
}

// ---------------------------------------------------------------------------
// 8-phase MFMA GEMM core (R4 structure — best measured loop: conflicts 0).
// K = 384 = 6 K-tiles of BK=64. 512 threads = 8 waves (WM x WN), per-wave
// 64x64 output. Ring of 3 LDS K-tile buffers. Staging 2 K-tiles ahead ->
// counted s_waitcnt vmcnt(9). Raw s_barrier. Slot-XOR swizzle on the READ
// side; inverse XOR pre-applied to per-lane GLOBAL source address.
// FROZEN: 5 schedule variants all measured 144-160 us.
// ---------------------------------------------------------------------------
template<int BM, int BN, int WM, int WN>
static __device__ __forceinline__ void gemm8(
    const unsigned short* __restrict__ A, const unsigned short* __restrict__ Bt,
    int m0, int n0, unsigned short* lds, f32x4 acc[4][4]) {

    constexpr int NA   = BM / 64;          // A stage-calls per K-tile (per thread)
    constexpr int BUFE = (BM + BN) * 64;   // elems per ring buffer

    const int tid  = threadIdx.x;
    const int wv   = tid >> 6;
    const int lane = tid & 63;
    const int wc = wv & (WN - 1), wr = wv / WN;
    const int lrow = lane & 15, lq = lane >> 4;
    const int lr8  = lane >> 3;                 // row within 8-row chunk
    const int gsl  = ((lane & 7) ^ lr8) << 3;   // inverse-swizzled slot, elems

#pragma unroll
    for (int i = 0; i < 4; i++)
#pragma unroll
        for (int j = 0; j < 4; j++) acc[i][j] = (f32x4){0.f, 0.f, 0.f, 0.f};

    auto stage = [&](int s, int kt, int bufi) {
        if (s < NA) {
            int grow = m0 + s * 64 + wv * 8 + lr8;
            gld_lds16(A + (size_t)grow * 384 + kt * 64 + gsl,
                      lds + bufi * BUFE + (s * 8 + wv) * 512);
        } else {
            int sj = s - NA;
            int grow = n0 + sj * 64 + wv * 8 + lr8;
            gld_lds16(Bt + (size_t)grow * 384 + kt * 64 + gsl,
                      lds + bufi * BUFE + BM * 64 + (sj * 8 + wv) * 512);
        }
    };

    // prologue: stage K-tiles 0 and 1 (12 loads outstanding per thread)
#pragma unroll
    for (int s = 0; s < 6; s++) stage(s, 0, 0);
#pragma unroll
    for (int s = 0; s < 6; s++) stage(s, 1, 1);

#pragma unroll
    for (int t = 0; t < 6; t++) {
        const int bufi = t % 3, nbuf = (t + 2) % 3;
        const unsigned short* la = lds + bufi * BUFE;
        const unsigned short* lb = la + BM * 64;
        bf16x8 af[4][2], bfr[2][2];

        // ------------- phase A (C cols 0..31 of wave tile) -------------
        if (t < 4) { stage(0, t + 2, nbuf); stage(1, t + 2, nbuf); stage(2, t + 2, nbuf); }
        if (t < 4)       asm volatile("s_waitcnt vmcnt(9)" ::: "memory");
        else if (t == 4) asm volatile("s_waitcnt vmcnt(6)" ::: "memory");
        else             asm volatile("s_waitcnt vmcnt(0)" ::: "memory");
        __builtin_amdgcn_sched_barrier(0);
        __builtin_amdgcn_s_barrier();   // collective: tile t ready everywhere

#pragma unroll
        for (int mi = 0; mi < 4; mi++)
#pragma unroll
            for (int ks = 0; ks < 2; ks++)
                af[mi][ks] = *(const bf16x8*)(la + (wr * 64 + mi * 16 + lrow) * 64 +
                                              (((ks * 4 + lq) ^ (lrow & 7)) << 3));
#pragma unroll
        for (int ni = 0; ni < 2; ni++)
#pragma unroll
            for (int ks = 0; ks < 2; ks++)
                bfr[ni][ks] = *(const bf16x8*)(lb + (wc * 64 + ni * 16 + lrow) * 64 +
                                               (((ks * 4 + lq) ^ (lrow & 7)) << 3));
        __builtin_amdgcn_s_setprio(1);
#pragma unroll
        for (int mi = 0; mi < 4; mi++)
#pragma unroll
            for (int ni = 0; ni < 2; ni++)
#pragma unroll
                for (int ks = 0; ks < 2; ks++)
                    acc[mi][ni] = __builtin_amdgcn_mfma_f32_16x16x32_bf16(
                        af[mi][ks], bfr[ni][ks], acc[mi][ni], 0, 0, 0);
        __builtin_amdgcn_s_setprio(0);
        __builtin_amdgcn_s_barrier();

        // ------------- phase B (C cols 32..63 of wave tile) -------------
        if (t < 4) { stage(3, t + 2, nbuf); stage(4, t + 2, nbuf); stage(5, t + 2, nbuf); }
        __builtin_amdgcn_s_barrier();
#pragma unroll
        for (int ni = 0; ni < 2; ni++)
#pragma unroll
            for (int ks = 0; ks < 2; ks++)
                bfr[ni][ks] = *(const bf16x8*)(lb + (wc * 64 + (ni + 2) * 16 + lrow) * 64 +
                                               (((ks * 4 + lq) ^ (lrow & 7)) << 3));
        __builtin_amdgcn_s_setprio(1);
#pragma unroll
        for (int mi = 0; mi < 4; mi++)
#pragma unroll
            for (int ni = 0; ni < 2; ni++)
#pragma unroll
                for (int ks = 0; ks < 2; ks++)
                    acc[mi][ni + 2] = __builtin_amdgcn_mfma_f32_16x16x32_bf16(
                        af[mi][ks], bfr[ni][ks], acc[mi][ni + 2], 0, 0, 0);
        __builtin_amdgcn_s_setprio(0);
        __builtin_amdgcn_s_barrier();
    }
}

// GEMM 1: qkv_t[p][o] = sum_c xt[p][c] * w_qkv[o][c]; output bf16, ldc = 1152
// BM=256 (p), BN=128 (o): grid 3528 = 8*441 (bijective XCD chunking).
__global__ __launch_bounds__(512) void gemm_qkv8(
    const unsigned short* __restrict__ A, const unsigned short* __restrict__ Bt,
    unsigned short* __restrict__ C) {
    __shared__ __align__(16) unsigned short lds[3 * (256 + 128) * 64];  // 144 KiB
    int lin = blockIdx.x;
    int xcd = lin & 7, pos = lin >> 3;
    int nid = xcd * 441 + pos;              // bijective: 3528 = 8*441
    int m0 = (nid / 9) * 256;
    int n0 = (nid % 9) * 128;
    f32x4 acc[4][4];
    gemm8<256, 128, 4, 2>(A, Bt, m0, n0, lds, acc);

    int lane = threadIdx.x & 63, wv = threadIdx.x >> 6;
    int wc = wv & 1, wr = wv >> 1;
    int lrow = lane & 15, lq = lane >> 4;
#pragma unroll
    for (int mi = 0; mi < 4; mi++)
#pragma unroll
        for (int ni = 0; ni < 4; ni++)
#pragma unroll
            for (int i = 0; i < 4; i++) {
                int row = m0 + wr * 64 + mi * 16 + lq * 4 + i;   // p
                int col = n0 + wc * 64 + ni * 16 + lrow;         // o
                C[(size_t)row * C3 + col] = f2bf(acc[mi][ni][i]);
            }
}

// GEMM 2: out[b][o][hw] = sum_c w_proj[o][c] * out_t[p][c] + b_proj[o]
// BM=128 (o), BN=256 (p): grid 1176 = 8*147. LDS-staged f32 coalesced
// epilogue (float4 1-KB bursts along hw; 3136%4==0 so no batch straddle).
__global__ __launch_bounds__(512) void gemm_proj8(
    const unsigned short* __restrict__ A, const unsigned short* __restrict__ Bt,
    const float* __restrict__ bias, float* __restrict__ out) {
    __shared__ __align__(16) unsigned short lds[3 * (128 + 256) * 64];  // 144 KiB
    int lin = blockIdx.x;
    int xcd = lin & 7, pos = lin >> 3;
    int nid = xcd * 147 + pos;              // bijective: 1176 = 8*147
    int m0 = (nid % 3) * 128;
    int n0 = (nid / 3) * 256;
    f32x4 acc[4][4];
    gemm8<128, 256, 2, 4>(A, Bt, m0, n0, lds, acc);

    int lane = threadIdx.x & 63, wv = threadIdx.x >> 6;
    int wc = wv & 3, wr = wv >> 2;
    int lrow = lane & 15, lq = lane >> 4;

    // stage C-tile (128 o x 256 p f32 = 128 KB) into LDS, bias folded
    float* sCf = (float*)lds;
#pragma unroll
    for (int mi = 0; mi < 4; mi++)
#pragma unroll
        for (int ni = 0; ni < 4; ni++)
#pragma unroll
            for (int i = 0; i < 4; i++) {
                int row = wr * 64 + mi * 16 + lq * 4 + i;   // local o
                int col = wc * 64 + ni * 16 + lrow;         // local p
                sCf[row * 256 + col] = acc[mi][ni][i] + bias[m0 + row];
            }
    __syncthreads();
    int r0   = threadIdx.x >> 6;   // 0..7
    int slot = threadIdx.x & 63;   // float4 slot
#pragma unroll
    for (int pass = 0; pass < 16; pass++) {
        int row = pass * 8 + r0;               // local o
        int p4  = n0 + slot * 4;               // global pixel (4-aligned)
        int b   = p4 / HW, hw = p4 - b * HW;   // float4 never straddles b
        float4 v = *(const float4*)(sCf + row * 256 + slot * 4);
        *(float4*)(out + (size_t)b * CDIM * HW + (size_t)(m0 + row) * HW + hw) = v;
    }
}

// ---------------------------------------------------------------------------
// Kernel 4: MFMA window attention. grid (2048, 12), block 64 (1 wave).
// (unchanged this round)
// ---------------------------------------------------------------------------
__global__ __launch_bounds__(64, 3) void attn_mfma(
    const unsigned short* __restrict__ qkv, const float* __restrict__ bias_t,
    unsigned short* __restrict__ outt) {
    int w = blockIdx.x, h = blockIdx.y;
    int lane = threadIdx.x;
    int q = lane >> 4, c15 = lane & 15;
    int b = w >> 6, wy = (w >> 3) & 7, wx = w & 7;
    int pbase = b * HW + wy * 7 * 56 + wx * 7;

    __shared__ __align__(16) unsigned short sVT[32 * 72];  // V^T[d][key]
    __shared__ __align__(16) unsigned short sP[64 * 72];   // P[query][key]

    int p_t[4]; int valid[4];
#pragma unroll
    for (int t = 0; t < 4; t++) {
        int tok = c15 + 16 * t;
        valid[t] = tok < 49;
        int tc = valid[t] ? tok : 48;
        p_t[t] = pbase + (tc / 7) * 56 + (tc % 7);
    }

    {
        uint4* z = (uint4*)sVT;
#pragma unroll
        for (int i = 0; i < 5; i++) {
            int idx = lane + 64 * i;
            if (idx < 288) z[idx] = (uint4){0u, 0u, 0u, 0u};
        }
    }

    bf16x8 kf[4], qf[4];
#pragma unroll
    for (int t = 0; t < 4; t++) {
        const unsigned short* base = qkv + (size_t)p_t[t] * C3 + h * HD + q * 8;
        qf[t] = *(const bf16x8*)(base);
        kf[t] = *(const bf16x8*)(base + CDIM);
    }

#pragma unroll
    for (int it = 0; it < 4; it++) {
        int c = lane + 64 * it;
        if (c < 196) {
            int tok = c >> 2, s = c & 3;
            int p = pbase + (tok / 7) * 56 + (tok % 7);
            uint4 v = *(const uint4*)(qkv + (size_t)p * C3 + 2 * CDIM + h * HD + s * 8);
            const unsigned short* vp = (const unsigned short*)&v;
#pragma unroll
            for (int i = 0; i < 8; i++)
                sVT[(8 * s + i) * 72 + tok] = vp[i];
        }
    }

    f32x4 acc[4][4];
    const float* bp = bias_t + (size_t)h * 64 * 64;
#pragma unroll
    for (int nt = 0; nt < 4; nt++) {
        const float* bq = bp + (c15 + 16 * nt) * 64 + 4 * q;
#pragma unroll
        for (int mt = 0; mt < 4; mt++)
            acc[mt][nt] = *(const f32x4*)(bq + 16 * mt);
    }

#pragma unroll
    for (int mt = 0; mt < 4; mt++)
#pragma unroll
        for (int nt = 0; nt < 4; nt++)
            acc[mt][nt] = __builtin_amdgcn_mfma_f32_16x16x32_bf16(
                kf[mt], qf[nt], acc[mt][nt], 0, 0, 0);

    const float KSC = 0.25503472f;                // 2^-2.5 * log2(e)
#pragma unroll
    for (int nt = 0; nt < 4; nt++) {
        float mx = acc[0][nt][0];
#pragma unroll
        for (int mt = 0; mt < 4; mt++)
#pragma unroll
            for (int r = 0; r < 4; r++) mx = fmaxf(mx, acc[mt][nt][r]);
        mx = fmaxf(mx, __shfl_xor(mx, 16));
        mx = fmaxf(mx, __shfl_xor(mx, 32));
        float sum = 0.f;
#pragma unroll
        for (int mt = 0; mt < 4; mt++)
#pragma unroll
            for (int r = 0; r < 4; r++) {
                float e = exp2f((acc[mt][nt][r] - mx) * KSC);
                acc[mt][nt][r] = e;
                sum += e;
            }
        sum += __shfl_xor(sum, 16);
        sum += __shfl_xor(sum, 32);
        float inv = 1.0f / sum;
#pragma unroll
        for (int mt = 0; mt < 4; mt++) {
            uint32_t u01 = pk2(acc[mt][nt][0] * inv, acc[mt][nt][1] * inv);
            uint32_t u23 = pk2(acc[mt][nt][2] * inv, acc[mt][nt][3] * inv);
            *(uint2*)(sP + (c15 + 16 * nt) * 72 + 4 * q + 16 * mt) =
                make_uint2(u01, u23);
        }
    }

    bf16x8 pf[4][2], vf[2][2];
#pragma unroll
    for (int nt = 0; nt < 4; nt++)
#pragma unroll
        for (int ks = 0; ks < 2; ks++)
            pf[nt][ks] = *(const bf16x8*)(sP + (c15 + 16 * nt) * 72 + q * 8 + 32 * ks);
#pragma unroll
    for (int mt = 0; mt < 2; mt++)
#pragma unroll
        for (int ks = 0; ks < 2; ks++)
            vf[mt][ks] = *(const bf16x8*)(sVT + (c15 + 16 * mt) * 72 + q * 8 + 32 * ks);

    f32x4 oacc[2][4];
#pragma unroll
    for (int mt = 0; mt < 2; mt++)
#pragma unroll
        for (int nt = 0; nt < 4; nt++)
            oacc[mt][nt] = (f32x4){0.f, 0.f, 0.f, 0.f};
#pragma unroll
    for (int ks = 0; ks < 2; ks++)
#pragma unroll
        for (int mt = 0; mt < 2; mt++)
#pragma unroll
            for (int nt = 0; nt < 4; nt++)
                oacc[mt][nt] = __builtin_amdgcn_mfma_f32_16x16x32_bf16(
                    vf[mt][ks], pf[nt][ks], oacc[mt][nt], 0, 0, 0);

#pragma unroll
    for (int nt = 0; nt < 4; nt++) {
        if (valid[nt]) {
            unsigned short* dst = outt + (size_t)p_t[nt] * CDIM + h * HD + 4 * q;
#pragma unroll
            for (int mt = 0; mt < 2; mt++) {
                uint32_t u01 = pk2(oacc[mt][nt][0], oacc[mt][nt][1]);
                uint32_t u23 = pk2(oacc[mt][nt][2], oacc[mt][nt][3]);
                *(uint2*)(dst + 16 * mt) = make_uint2(u01, u23);
            }
        }
    }
}

// ---------------------------------------------------------------------------
// Launch (4 kernels, was 7)
// ---------------------------------------------------------------------------
extern "C" void kernel_launch(void* const* d_in, const int* in_sizes, int n_in,
                              void* d_out, int out_size, void* d_ws, size_t ws_size,
                              hipStream_t stream) {
    const float* x      = (const float*)d_in[0];
    const float* w_qkv  = (const float*)d_in[1];
    const float* btab   = (const float*)d_in[2];
    const float* w_proj = (const float*)d_in[3];
    const float* b_proj = (const float*)d_in[4];
    float* out = (float*)d_out;

    // workspace layout (bytes)
    char* ws = (char*)d_ws;
    const size_t off_xt   = 0;                         // 77,070,336 (reused as out_t)
    const size_t off_qkv  = 77070336;                  // 231,211,008
    const size_t off_wq   = off_qkv + 231211008;       // 884,736
    const size_t off_wp   = off_wq + 884736;           // 294,912
    const size_t off_bt   = off_wp + 294912;           // 196,608
    unsigned short* xt   = (unsigned short*)(ws + off_xt);
    unsigned short* qkvt = (unsigned short*)(ws + off_qkv);
    unsigned short* wqb  = (unsigned short*)(ws + off_wq);
    unsigned short* wpb  = (unsigned short*)(ws + off_wp);
    float*          bt   = (float*)(ws + off_bt);
    unsigned short* outt = xt;   // alias: xt dead after gemm_qkv

    prep_transpose<<<10176, 256, 0, stream>>>(x, w_qkv, w_proj, btab, wqb, wpb, bt, xt);
    gemm_qkv8<<<3528, 512, 0, stream>>>(xt, wqb, qkvt);
    attn_mfma<<<dim3(NWIN, NHEAD), 64, 0, stream>>>(qkvt, bt, outt);
    gemm_proj8<<<1176, 512, 0, stream>>>(wpb, outt, b_proj, out);
}